// Round 1
// baseline (1071.910 us; speedup 1.0000x reference)
//
#include <hip/hip_runtime.h>
#include <stdint.h>

typedef __attribute__((ext_vector_type(4))) float  f32x4;
typedef __attribute__((ext_vector_type(8))) short  bf16x8;

#define BATCH   64
#define SRC_LEN 2048
#define HID     1024
#define M_TOT   (BATCH*SRC_LEN)   // 131072

#define BM 128
#define BN 128
#define BK 64
#define NT (HID/BK)               // 16 k-steps

__device__ __forceinline__ short f2bf(float f) {
  // round-to-nearest-even fp32 -> bf16 (no NaN handling needed for this data)
  unsigned u = __builtin_bit_cast(unsigned, f);
  u += 0x7fffu + ((u >> 16) & 1u);
  return (short)(u >> 16);
}

// ---------------- kernel 0: w_en_w fp32 -> bf16 (2 MB into ws) ----------------
__global__ void k_convert_w(const float* __restrict__ w, short* __restrict__ wb) {
  int i = (blockIdx.x * 256 + threadIdx.x) * 8;
  f32x4 a = *(const f32x4*)(w + i);
  f32x4 b = *(const f32x4*)(w + i + 4);
  bf16x8 o;
  o[0]=f2bf(a[0]); o[1]=f2bf(a[1]); o[2]=f2bf(a[2]); o[3]=f2bf(a[3]);
  o[4]=f2bf(b[0]); o[5]=f2bf(b[1]); o[6]=f2bf(b[2]); o[7]=f2bf(b[3]);
  *(bf16x8*)(wb + i) = o;
}

// ---------------- kernel 1: bias_all[b][d] = w_en_b + w_de_b + hidden[b]·w_de_w[d] ----------------
__global__ void k_bias(const float* __restrict__ hidden, const float* __restrict__ w_de_w,
                       const float* __restrict__ w_en_b, const float* __restrict__ w_de_b,
                       float* __restrict__ bias_all) {
  __shared__ float hid[HID];
  int b  = blockIdx.x >> 2;
  int dc = blockIdx.x & 3;
  for (int i = threadIdx.x; i < HID; i += 256) hid[i] = hidden[b*HID + i];
  __syncthreads();
  int d = dc*256 + threadIdx.x;
  const f32x4* wrow = (const f32x4*)(w_de_w + (size_t)d*HID);
  float acc = 0.f;
  #pragma unroll 8
  for (int q = 0; q < HID/4; ++q) {
    f32x4 w4 = wrow[q];
    f32x4 h4 = *(const f32x4*)&hid[q*4];
    acc += w4[0]*h4[0] + w4[1]*h4[1] + w4[2]*h4[2] + w4[3]*h4[3];
  }
  bias_all[b*HID + d] = acc + w_en_b[d] + w_de_b[d];
}

// ---------------- kernel 2: GEMM (bf16 MFMA) fused with tanh·v partial-score epilogue ----------------
// scores[m] += sum_{n in block range} tanh(acc[m][n] + bias_all[b][n]) * v_w[n]
__global__ void __launch_bounds__(256) k_gemm_score(
    const float* __restrict__ A,        // en_output (M x K) fp32
    const short* __restrict__ Bw,       // w_en bf16 (N x K)  (B^T layout: K contiguous)
    const float* __restrict__ bias_all, // (BATCH x N)
    const float* __restrict__ v_w,      // (N)
    float* __restrict__ scores)         // (M), pre-zeroed, atomic accumulate
{
  __shared__ short As[BM][BK];   // 16 KB
  __shared__ short Bs[BN][BK];   // 16 KB

  // Same-XCD sibling swizzle: 8 n-blocks of one m-panel -> consecutive ids on one XCD
  int raw  = blockIdx.x;
  int xcd  = raw & 7;
  int idx  = raw >> 3;                         // 0..1023
  int mblk = xcd * (M_TOT/BM/8) + (idx >> 3);  // 128 panels per XCD
  int nblk = idx & 7;
  int m0 = mblk * BM, n0 = nblk * BN;

  int tid  = threadIdx.x;
  int lane = tid & 63;
  int wid  = tid >> 6;          // 4 waves, 2x2
  int wr = wid >> 1, wc = wid & 1;
  int fr  = lane & 15;
  int fko = (lane >> 4) * 8;    // k-offset within 64-wide row

  f32x4 acc[4][4] = {};

  // A staging: thread covers row ar, 32 cols starting at ac (2 threads/row)
  int ar = tid >> 1;
  int ac = (tid & 1) * 32;
  const float* aBase = A + (size_t)(m0 + ar) * HID + ac;

  f32x4 aReg[8];
  #pragma unroll
  for (int i = 0; i < 8; ++i) aReg[i] = *(const f32x4*)(aBase + i*4);

  for (int kt = 0; kt < NT; ++kt) {
    __syncthreads();  // previous tile's readers done
    // A: convert fp32->bf16, write to LDS (4 x ds_write_b128)
    #pragma unroll
    for (int g = 0; g < 4; ++g) {
      bf16x8 w;
      w[0]=f2bf(aReg[2*g][0]);   w[1]=f2bf(aReg[2*g][1]);
      w[2]=f2bf(aReg[2*g][2]);   w[3]=f2bf(aReg[2*g][3]);
      w[4]=f2bf(aReg[2*g+1][0]); w[5]=f2bf(aReg[2*g+1][1]);
      w[6]=f2bf(aReg[2*g+1][2]); w[7]=f2bf(aReg[2*g+1][3]);
      *(bf16x8*)&As[ar][ac + g*8] = w;
    }
    // B: async global->LDS, 16 B per lane, 4 calls (16 KB tile)
    #pragma unroll
    for (int j = 0; j < 4; ++j) {
      int chunk = j*256 + tid;                 // 16B chunk index in [0,1024)
      const short* src = Bw + (size_t)(n0 + (chunk >> 3)) * HID + kt*BK + (chunk & 7)*8;
      __builtin_amdgcn_global_load_lds(
          (const __attribute__((address_space(1))) void*)src,
          (__attribute__((address_space(3))) void*)((char*)&Bs[0][0] + chunk*16),
          16, 0, 0);
    }
    __syncthreads();  // staged data visible (compiler drains vmcnt here)

    // Prefetch next A tile: issued now so HBM latency hides under MFMA phase
    if (kt + 1 < NT) {
      const float* nxt = aBase + (kt+1)*BK;
      #pragma unroll
      for (int i = 0; i < 8; ++i) aReg[i] = *(const f32x4*)(nxt + i*4);
    }

    #pragma unroll
    for (int kk = 0; kk < 2; ++kk) {
      bf16x8 aF[4], bF[4];
      #pragma unroll
      for (int mi = 0; mi < 4; ++mi)
        aF[mi] = *(const bf16x8*)&As[wr*64 + mi*16 + fr][kk*32 + fko];
      #pragma unroll
      for (int ni = 0; ni < 4; ++ni)
        bF[ni] = *(const bf16x8*)&Bs[wc*64 + ni*16 + fr][kk*32 + fko];
      #pragma unroll
      for (int mi = 0; mi < 4; ++mi)
        #pragma unroll
        for (int ni = 0; ni < 4; ++ni)
          acc[mi][ni] = __builtin_amdgcn_mfma_f32_16x16x32_bf16(aF[mi], bF[ni], acc[mi][ni], 0, 0, 0);
    }
  }

  // Epilogue: energy = tanh(acc + bias), partial score = sum_n energy*v
  int b = m0 >> 11;   // 2048 rows per batch, BM divides 2048 so no straddle
  float vv[4], bb[4];
  #pragma unroll
  for (int ni = 0; ni < 4; ++ni) {
    int col = n0 + wc*64 + ni*16 + fr;
    vv[ni] = v_w[col];
    bb[ni] = bias_all[b*HID + col];
  }
  #pragma unroll
  for (int mi = 0; mi < 4; ++mi) {
    #pragma unroll
    for (int j = 0; j < 4; ++j) {
      float p = 0.f;
      #pragma unroll
      for (int ni = 0; ni < 4; ++ni)
        p += tanhf(acc[mi][ni][j] + bb[ni]) * vv[ni];
      // reduce across the 16 lanes sharing this row (C/D: col=lane&15, row=(lane>>4)*4+j)
      p += __shfl_xor(p, 1);
      p += __shfl_xor(p, 2);
      p += __shfl_xor(p, 4);
      p += __shfl_xor(p, 8);
      if (fr == 0) {
        int row = wr*64 + mi*16 + ((lane >> 4) << 2) + j;
        atomicAdd(&scores[m0 + row], p);
      }
    }
  }
}

// ---------------- kernel 3: in-place softmax over S per batch ----------------
__global__ void k_softmax(float* __restrict__ attn) {
  int b = blockIdx.x;
  float* row = attn + (size_t)b * SRC_LEN;
  int tid = threadIdx.x, lane = tid & 63, wid = tid >> 6;
  __shared__ float red[4];
  float v[8];
  #pragma unroll
  for (int i = 0; i < 8; ++i) v[i] = row[tid + i*256];
  float mx = v[0];
  #pragma unroll
  for (int i = 1; i < 8; ++i) mx = fmaxf(mx, v[i]);
  #pragma unroll
  for (int o = 32; o; o >>= 1) mx = fmaxf(mx, __shfl_xor(mx, o));
  if (lane == 0) red[wid] = mx;
  __syncthreads();
  mx = fmaxf(fmaxf(red[0], red[1]), fmaxf(red[2], red[3]));
  float s = 0.f;
  #pragma unroll
  for (int i = 0; i < 8; ++i) { v[i] = __expf(v[i] - mx); s += v[i]; }
  #pragma unroll
  for (int o = 32; o; o >>= 1) s += __shfl_xor(s, o);
  __syncthreads();
  if (lane == 0) red[wid] = s;
  __syncthreads();
  s = red[0] + red[1] + red[2] + red[3];
  float inv = 1.f / s;
  #pragma unroll
  for (int i = 0; i < 8; ++i) row[tid + i*256] = v[i] * inv;
}

// ---------------- kernel 4: weighted[b,e] = sum_s attn[b,s] * en[b,s,e] ----------------
__global__ void k_weighted(const float* __restrict__ en, const float* __restrict__ attn,
                           float* __restrict__ outw) {
  int b  = blockIdx.x >> 4;
  int sc = blockIdx.x & 15;
  __shared__ float aw[128];
  int tid = threadIdx.x;
  if (tid < 128) aw[tid] = attn[b*SRC_LEN + sc*128 + tid];
  __syncthreads();
  const float* base = en + ((size_t)b*SRC_LEN + sc*128) * HID + tid*4;
  f32x4 acc = {0.f, 0.f, 0.f, 0.f};
  #pragma unroll 8
  for (int s = 0; s < 128; ++s) {
    f32x4 x = *(const f32x4*)(base + (size_t)s*HID);
    float w = aw[s];
    acc[0] += w*x[0]; acc[1] += w*x[1]; acc[2] += w*x[2]; acc[3] += w*x[3];
  }
  float* o = outw + b*HID + tid*4;
  atomicAdd(o+0, acc[0]); atomicAdd(o+1, acc[1]);
  atomicAdd(o+2, acc[2]); atomicAdd(o+3, acc[3]);
}

extern "C" void kernel_launch(void* const* d_in, const int* in_sizes, int n_in,
                              void* d_out, int out_size, void* d_ws, size_t ws_size,
                              hipStream_t stream) {
  const float* hidden = (const float*)d_in[0];
  const float* en     = (const float*)d_in[1];
  const float* w_en_w = (const float*)d_in[2];
  const float* w_en_b = (const float*)d_in[3];
  const float* w_de_w = (const float*)d_in[4];
  const float* w_de_b = (const float*)d_in[5];
  const float* v_w    = (const float*)d_in[6];

  float* outw = (float*)d_out;              // (B, 1, E) = 65536 floats
  float* attn = outw + BATCH*HID;           // (B, S)    = 131072 floats (scores -> attention in place)

  short* w_bf     = (short*)d_ws;                                      // 2 MB bf16 weights
  float* bias_all = (float*)((char*)d_ws + (size_t)HID*HID*sizeof(short)); // 256 KB

  // zero outputs (weighted accumulated atomically; scores accumulated atomically)
  hipMemsetAsync(d_out, 0, (size_t)out_size * sizeof(float), stream);

  k_convert_w<<<dim3(HID*HID/(256*8)), dim3(256), 0, stream>>>(w_en_w, w_bf);
  k_bias<<<dim3(BATCH*4), dim3(256), 0, stream>>>(hidden, w_de_w, w_en_b, w_de_b, bias_all);
  k_gemm_score<<<dim3((M_TOT/BM)*(HID/BN)), dim3(256), 0, stream>>>(en, w_bf, bias_all, v_w, attn);
  k_softmax<<<dim3(BATCH), dim3(256), 0, stream>>>(attn);
  k_weighted<<<dim3(BATCH*16), dim3(256), 0, stream>>>(en, attn, outw);
}

// Round 2
// 837.269 us; speedup vs baseline: 1.2802x; 1.2802x over previous
//
#include <hip/hip_runtime.h>
#include <stdint.h>

typedef __attribute__((ext_vector_type(4))) float  f32x4;
typedef __attribute__((ext_vector_type(8))) short  bf16x8;

#define BATCH   64
#define SRC_LEN 2048
#define HID     1024
#define M_TOT   (BATCH*SRC_LEN)   // 131072

#define BM 128
#define BN 128
#define BK 64
#define NT (HID/BK)               // 16 k-steps

__device__ __forceinline__ short f2bf(float f) {
  unsigned u = __builtin_bit_cast(unsigned, f);
  u += 0x7fffu + ((u >> 16) & 1u);
  return (short)(u >> 16);
}

// ---------------- kernel 0a: w_en_w fp32 -> bf16 (2 MB) ----------------
__global__ void k_convert_w(const float* __restrict__ w, short* __restrict__ wb) {
  int i = (blockIdx.x * 256 + threadIdx.x) * 8;
  f32x4 a = *(const f32x4*)(w + i);
  f32x4 b = *(const f32x4*)(w + i + 4);
  bf16x8 o;
  o[0]=f2bf(a[0]); o[1]=f2bf(a[1]); o[2]=f2bf(a[2]); o[3]=f2bf(a[3]);
  o[4]=f2bf(b[0]); o[5]=f2bf(b[1]); o[6]=f2bf(b[2]); o[7]=f2bf(b[3]);
  *(bf16x8*)(wb + i) = o;
}

// ---------------- kernel 0b: en_output fp32 -> bf16 (256 MB), grid-stride ----------------
__global__ void k_convert_en(const float* __restrict__ in, short* __restrict__ out) {
  size_t stride = (size_t)gridDim.x * 256 * 8;
  size_t base = ((size_t)blockIdx.x * 256 + threadIdx.x) * 8;
  size_t total = (size_t)M_TOT * HID;
  for (; base < total; base += stride) {
    f32x4 a = *(const f32x4*)(in + base);
    f32x4 b = *(const f32x4*)(in + base + 4);
    bf16x8 o;
    o[0]=f2bf(a[0]); o[1]=f2bf(a[1]); o[2]=f2bf(a[2]); o[3]=f2bf(a[3]);
    o[4]=f2bf(b[0]); o[5]=f2bf(b[1]); o[6]=f2bf(b[2]); o[7]=f2bf(b[3]);
    *(bf16x8*)(out + base) = o;
  }
}

// ---------------- kernel 1: bias_all[b][d] = w_en_b + w_de_b + hidden[b]·w_de_w[d] ----------------
__global__ void k_bias(const float* __restrict__ hidden, const float* __restrict__ w_de_w,
                       const float* __restrict__ w_en_b, const float* __restrict__ w_de_b,
                       float* __restrict__ bias_all) {
  __shared__ float hid[HID];
  int b  = blockIdx.x >> 2;
  int dc = blockIdx.x & 3;
  for (int i = threadIdx.x; i < HID; i += 256) hid[i] = hidden[b*HID + i];
  __syncthreads();
  int d = dc*256 + threadIdx.x;
  const f32x4* wrow = (const f32x4*)(w_de_w + (size_t)d*HID);
  float acc = 0.f;
  #pragma unroll 8
  for (int q = 0; q < HID/4; ++q) {
    f32x4 w4 = wrow[q];
    f32x4 h4 = *(const f32x4*)&hid[q*4];
    acc += w4[0]*h4[0] + w4[1]*h4[1] + w4[2]*h4[2] + w4[3]*h4[3];
  }
  bias_all[b*HID + d] = acc + w_en_b[d] + w_de_b[d];
}

// ---------------- kernel 2 (fast): m97-structure GEMM, both operands global_load_lds ----------------
__global__ void __launch_bounds__(256) k_gemm_score_fast(
    const short* __restrict__ Abf,      // en_output bf16 (M x K)
    const short* __restrict__ Bw,       // w_en bf16 (N x K)
    const float* __restrict__ bias_all, // (BATCH x N)
    const float* __restrict__ v_w,      // (N)
    float* __restrict__ scores)         // (M), pre-zeroed, atomic accumulate
{
  __shared__ short As[BM][BK];   // 16 KB
  __shared__ short Bs[BN][BK];   // 16 KB

  // Same-XCD sibling swizzle: the 8 n-blocks of one m-panel land on one XCD -> A panel fetched once
  int raw  = blockIdx.x;
  int xcd  = raw & 7;
  int idx  = raw >> 3;
  int mblk = xcd * (M_TOT/BM/8) + (idx >> 3);
  int nblk = idx & 7;
  int m0 = mblk * BM, n0 = nblk * BN;

  int tid  = threadIdx.x;
  int lane = tid & 63;
  int wid  = tid >> 6;
  int wr = wid >> 1, wc = wid & 1;
  int fr  = lane & 15;
  int fko = (lane >> 4) * 8;

  f32x4 acc[4][4] = {};

  for (int kt = 0; kt < NT; ++kt) {
    __syncthreads();   // readers of previous tile done
    #pragma unroll
    for (int j = 0; j < 4; ++j) {
      int c = j*256 + tid;   // 16B chunk in [0,1024): row=c>>3, col8=c&7
      const short* srcA = Abf + (size_t)(m0 + (c >> 3)) * HID + kt*BK + (c & 7)*8;
      __builtin_amdgcn_global_load_lds(
          (const __attribute__((address_space(1))) void*)srcA,
          (__attribute__((address_space(3))) void*)((char*)&As[0][0] + c*16),
          16, 0, 0);
    }
    #pragma unroll
    for (int j = 0; j < 4; ++j) {
      int c = j*256 + tid;
      const short* srcB = Bw + (size_t)(n0 + (c >> 3)) * HID + kt*BK + (c & 7)*8;
      __builtin_amdgcn_global_load_lds(
          (const __attribute__((address_space(1))) void*)srcB,
          (__attribute__((address_space(3))) void*)((char*)&Bs[0][0] + c*16),
          16, 0, 0);
    }
    __syncthreads();   // vmcnt drained by compiler before barrier

    #pragma unroll
    for (int kk = 0; kk < 2; ++kk) {
      bf16x8 aF[4], bF[4];
      #pragma unroll
      for (int mi = 0; mi < 4; ++mi)
        aF[mi] = *(const bf16x8*)&As[wr*64 + mi*16 + fr][kk*32 + fko];
      #pragma unroll
      for (int ni = 0; ni < 4; ++ni)
        bF[ni] = *(const bf16x8*)&Bs[wc*64 + ni*16 + fr][kk*32 + fko];
      #pragma unroll
      for (int mi = 0; mi < 4; ++mi)
        #pragma unroll
        for (int ni = 0; ni < 4; ++ni)
          acc[mi][ni] = __builtin_amdgcn_mfma_f32_16x16x32_bf16(aF[mi], bF[ni], acc[mi][ni], 0, 0, 0);
    }
  }

  // Epilogue: energy = tanh(acc + bias), partial score = sum_n energy*v
  int b = m0 >> 11;
  float vv[4], bb[4];
  #pragma unroll
  for (int ni = 0; ni < 4; ++ni) {
    int col = n0 + wc*64 + ni*16 + fr;
    vv[ni] = v_w[col];
    bb[ni] = bias_all[b*HID + col];
  }
  #pragma unroll
  for (int mi = 0; mi < 4; ++mi) {
    #pragma unroll
    for (int j = 0; j < 4; ++j) {
      float p = 0.f;
      #pragma unroll
      for (int ni = 0; ni < 4; ++ni)
        p += tanhf(acc[mi][ni][j] + bb[ni]) * vv[ni];
      p += __shfl_xor(p, 1);
      p += __shfl_xor(p, 2);
      p += __shfl_xor(p, 4);
      p += __shfl_xor(p, 8);
      if (fr == 0) {
        int row = wr*64 + mi*16 + ((lane >> 4) << 2) + j;
        atomicAdd(&scores[m0 + row], p);
      }
    }
  }
}

// ---------------- kernel 2 (fallback): round-1 GEMM with in-kernel A conversion ----------------
__global__ void __launch_bounds__(256) k_gemm_score_conv(
    const float* __restrict__ A, const short* __restrict__ Bw,
    const float* __restrict__ bias_all, const float* __restrict__ v_w,
    float* __restrict__ scores)
{
  __shared__ short As[BM][BK];
  __shared__ short Bs[BN][BK];
  int raw  = blockIdx.x;
  int xcd  = raw & 7;
  int idx  = raw >> 3;
  int mblk = xcd * (M_TOT/BM/8) + (idx >> 3);
  int nblk = idx & 7;
  int m0 = mblk * BM, n0 = nblk * BN;
  int tid  = threadIdx.x;
  int lane = tid & 63;
  int wid  = tid >> 6;
  int wr = wid >> 1, wc = wid & 1;
  int fr  = lane & 15;
  int fko = (lane >> 4) * 8;
  f32x4 acc[4][4] = {};
  int ar = tid >> 1;
  int ac = (tid & 1) * 32;
  const float* aBase = A + (size_t)(m0 + ar) * HID + ac;
  f32x4 aReg[8];
  #pragma unroll
  for (int i = 0; i < 8; ++i) aReg[i] = *(const f32x4*)(aBase + i*4);
  for (int kt = 0; kt < NT; ++kt) {
    __syncthreads();
    #pragma unroll
    for (int g = 0; g < 4; ++g) {
      bf16x8 w;
      w[0]=f2bf(aReg[2*g][0]);   w[1]=f2bf(aReg[2*g][1]);
      w[2]=f2bf(aReg[2*g][2]);   w[3]=f2bf(aReg[2*g][3]);
      w[4]=f2bf(aReg[2*g+1][0]); w[5]=f2bf(aReg[2*g+1][1]);
      w[6]=f2bf(aReg[2*g+1][2]); w[7]=f2bf(aReg[2*g+1][3]);
      *(bf16x8*)&As[ar][ac + g*8] = w;
    }
    #pragma unroll
    for (int j = 0; j < 4; ++j) {
      int c = j*256 + tid;
      const short* src = Bw + (size_t)(n0 + (c >> 3)) * HID + kt*BK + (c & 7)*8;
      __builtin_amdgcn_global_load_lds(
          (const __attribute__((address_space(1))) void*)src,
          (__attribute__((address_space(3))) void*)((char*)&Bs[0][0] + c*16),
          16, 0, 0);
    }
    __syncthreads();
    if (kt + 1 < NT) {
      const float* nxt = aBase + (kt+1)*BK;
      #pragma unroll
      for (int i = 0; i < 8; ++i) aReg[i] = *(const f32x4*)(nxt + i*4);
    }
    #pragma unroll
    for (int kk = 0; kk < 2; ++kk) {
      bf16x8 aF[4], bF[4];
      #pragma unroll
      for (int mi = 0; mi < 4; ++mi)
        aF[mi] = *(const bf16x8*)&As[wr*64 + mi*16 + fr][kk*32 + fko];
      #pragma unroll
      for (int ni = 0; ni < 4; ++ni)
        bF[ni] = *(const bf16x8*)&Bs[wc*64 + ni*16 + fr][kk*32 + fko];
      #pragma unroll
      for (int mi = 0; mi < 4; ++mi)
        #pragma unroll
        for (int ni = 0; ni < 4; ++ni)
          acc[mi][ni] = __builtin_amdgcn_mfma_f32_16x16x32_bf16(aF[mi], bF[ni], acc[mi][ni], 0, 0, 0);
    }
  }
  int b = m0 >> 11;
  float vv[4], bb[4];
  #pragma unroll
  for (int ni = 0; ni < 4; ++ni) {
    int col = n0 + wc*64 + ni*16 + fr;
    vv[ni] = v_w[col];
    bb[ni] = bias_all[b*HID + col];
  }
  #pragma unroll
  for (int mi = 0; mi < 4; ++mi) {
    #pragma unroll
    for (int j = 0; j < 4; ++j) {
      float p = 0.f;
      #pragma unroll
      for (int ni = 0; ni < 4; ++ni)
        p += tanhf(acc[mi][ni][j] + bb[ni]) * vv[ni];
      p += __shfl_xor(p, 1);
      p += __shfl_xor(p, 2);
      p += __shfl_xor(p, 4);
      p += __shfl_xor(p, 8);
      if (fr == 0) {
        int row = wr*64 + mi*16 + ((lane >> 4) << 2) + j;
        atomicAdd(&scores[m0 + row], p);
      }
    }
  }
}

// ---------------- kernel 3: in-place softmax over S per batch ----------------
__global__ void k_softmax(float* __restrict__ attn) {
  int b = blockIdx.x;
  float* row = attn + (size_t)b * SRC_LEN;
  int tid = threadIdx.x, lane = tid & 63, wid = tid >> 6;
  __shared__ float red[4];
  float v[8];
  #pragma unroll
  for (int i = 0; i < 8; ++i) v[i] = row[tid + i*256];
  float mx = v[0];
  #pragma unroll
  for (int i = 1; i < 8; ++i) mx = fmaxf(mx, v[i]);
  #pragma unroll
  for (int o = 32; o; o >>= 1) mx = fmaxf(mx, __shfl_xor(mx, o));
  if (lane == 0) red[wid] = mx;
  __syncthreads();
  mx = fmaxf(fmaxf(red[0], red[1]), fmaxf(red[2], red[3]));
  float s = 0.f;
  #pragma unroll
  for (int i = 0; i < 8; ++i) { v[i] = __expf(v[i] - mx); s += v[i]; }
  #pragma unroll
  for (int o = 32; o; o >>= 1) s += __shfl_xor(s, o);
  __syncthreads();
  if (lane == 0) red[wid] = s;
  __syncthreads();
  s = red[0] + red[1] + red[2] + red[3];
  float inv = 1.f / s;
  #pragma unroll
  for (int i = 0; i < 8; ++i) row[tid + i*256] = v[i] * inv;
}

// ---------------- kernel 4: weighted[b,e] = sum_s attn[b,s] * en[b,s,e] ----------------
__global__ void k_weighted(const float* __restrict__ en, const float* __restrict__ attn,
                           float* __restrict__ outw) {
  int b  = blockIdx.x >> 4;
  int sc = blockIdx.x & 15;
  __shared__ float aw[128];
  int tid = threadIdx.x;
  if (tid < 128) aw[tid] = attn[b*SRC_LEN + sc*128 + tid];
  __syncthreads();
  const float* base = en + ((size_t)b*SRC_LEN + sc*128) * HID + tid*4;
  f32x4 acc = {0.f, 0.f, 0.f, 0.f};
  #pragma unroll 8
  for (int s = 0; s < 128; ++s) {
    f32x4 x = *(const f32x4*)(base + (size_t)s*HID);
    float w = aw[s];
    acc[0] += w*x[0]; acc[1] += w*x[1]; acc[2] += w*x[2]; acc[3] += w*x[3];
  }
  float* o = outw + b*HID + tid*4;
  atomicAdd(o+0, acc[0]); atomicAdd(o+1, acc[1]);
  atomicAdd(o+2, acc[2]); atomicAdd(o+3, acc[3]);
}

extern "C" void kernel_launch(void* const* d_in, const int* in_sizes, int n_in,
                              void* d_out, int out_size, void* d_ws, size_t ws_size,
                              hipStream_t stream) {
  const float* hidden = (const float*)d_in[0];
  const float* en     = (const float*)d_in[1];
  const float* w_en_w = (const float*)d_in[2];
  const float* w_en_b = (const float*)d_in[3];
  const float* w_de_w = (const float*)d_in[4];
  const float* w_de_b = (const float*)d_in[5];
  const float* v_w    = (const float*)d_in[6];

  float* outw = (float*)d_out;              // (B, 1, E)
  float* attn = outw + BATCH*HID;           // (B, S) scores -> attention in place

  const size_t en_elems = (size_t)M_TOT * HID;
  const size_t need_fast = en_elems*sizeof(short) + (size_t)HID*HID*sizeof(short)
                         + (size_t)BATCH*HID*sizeof(float);

  hipMemsetAsync(d_out, 0, (size_t)out_size * sizeof(float), stream);

  if (ws_size >= need_fast) {
    short* en_bf    = (short*)d_ws;                       // 256 MB
    short* w_bf     = en_bf + en_elems;                   // 2 MB
    float* bias_all = (float*)(w_bf + (size_t)HID*HID);   // 256 KB

    k_convert_en<<<dim3(2048), dim3(256), 0, stream>>>(en, en_bf);
    k_convert_w<<<dim3(HID*HID/(256*8)), dim3(256), 0, stream>>>(w_en_w, w_bf);
    k_bias<<<dim3(BATCH*4), dim3(256), 0, stream>>>(hidden, w_de_w, w_en_b, w_de_b, bias_all);
    k_gemm_score_fast<<<dim3((M_TOT/BM)*(HID/BN)), dim3(256), 0, stream>>>(en_bf, w_bf, bias_all, v_w, attn);
  } else {
    short* w_bf     = (short*)d_ws;
    float* bias_all = (float*)((char*)d_ws + (size_t)HID*HID*sizeof(short));
    k_convert_w<<<dim3(HID*HID/(256*8)), dim3(256), 0, stream>>>(w_en_w, w_bf);
    k_bias<<<dim3(BATCH*4), dim3(256), 0, stream>>>(hidden, w_de_w, w_en_b, w_de_b, bias_all);
    k_gemm_score_conv<<<dim3((M_TOT/BM)*(HID/BN)), dim3(256), 0, stream>>>(en, w_bf, bias_all, v_w, attn);
  }

  k_softmax<<<dim3(BATCH), dim3(256), 0, stream>>>(attn);
  k_weighted<<<dim3(BATCH*16), dim3(256), 0, stream>>>(en, attn, outw);
}

// Round 3
// 785.527 us; speedup vs baseline: 1.3646x; 1.0659x over previous
//
#include <hip/hip_runtime.h>
#include <stdint.h>

typedef __attribute__((ext_vector_type(4))) float  f32x4;
typedef __attribute__((ext_vector_type(8))) short  bf16x8;

#define BATCH   64
#define SRC_LEN 2048
#define HID     1024
#define M_TOT   (BATCH*SRC_LEN)   // 131072

#define BM 128
#define BN 128
#define BK 64
#define NT (HID/BK)               // 16 k-steps

__device__ __forceinline__ short f2bf(float f) {
  unsigned u = __builtin_bit_cast(unsigned, f);
  u += 0x7fffu + ((u >> 16) & 1u);
  return (short)(u >> 16);
}

// ---------------- kernel 0a: w_en_w fp32 -> bf16 (2 MB) ----------------
__global__ void k_convert_w(const float* __restrict__ w, short* __restrict__ wb) {
  int i = (blockIdx.x * 256 + threadIdx.x) * 8;
  f32x4 a = *(const f32x4*)(w + i);
  f32x4 b = *(const f32x4*)(w + i + 4);
  bf16x8 o;
  o[0]=f2bf(a[0]); o[1]=f2bf(a[1]); o[2]=f2bf(a[2]); o[3]=f2bf(a[3]);
  o[4]=f2bf(b[0]); o[5]=f2bf(b[1]); o[6]=f2bf(b[2]); o[7]=f2bf(b[3]);
  *(bf16x8*)(wb + i) = o;
}

// ---------------- kernel 0b: en_output fp32 -> bf16 (256 MB), grid-stride ----------------
__global__ void k_convert_en(const float* __restrict__ in, short* __restrict__ out) {
  size_t stride = (size_t)gridDim.x * 256 * 8;
  size_t base = ((size_t)blockIdx.x * 256 + threadIdx.x) * 8;
  size_t total = (size_t)M_TOT * HID;
  for (; base < total; base += stride) {
    f32x4 a = *(const f32x4*)(in + base);
    f32x4 b = *(const f32x4*)(in + base + 4);
    bf16x8 o;
    o[0]=f2bf(a[0]); o[1]=f2bf(a[1]); o[2]=f2bf(a[2]); o[3]=f2bf(a[3]);
    o[4]=f2bf(b[0]); o[5]=f2bf(b[1]); o[6]=f2bf(b[2]); o[7]=f2bf(b[3]);
    *(bf16x8*)(out + base) = o;
  }
}

// ---------------- kernel 1: bias_all[b][d] = w_en_b + w_de_b + hidden[b]·w_de_w[d] ----------------
__global__ void k_bias(const float* __restrict__ hidden, const float* __restrict__ w_de_w,
                       const float* __restrict__ w_en_b, const float* __restrict__ w_de_b,
                       float* __restrict__ bias_all) {
  __shared__ float hid[HID];
  int b  = blockIdx.x >> 2;
  int dc = blockIdx.x & 3;
  for (int i = threadIdx.x; i < HID; i += 256) hid[i] = hidden[b*HID + i];
  __syncthreads();
  int d = dc*256 + threadIdx.x;
  const f32x4* wrow = (const f32x4*)(w_de_w + (size_t)d*HID);
  float acc = 0.f;
  #pragma unroll 8
  for (int q = 0; q < HID/4; ++q) {
    f32x4 w4 = wrow[q];
    f32x4 h4 = *(const f32x4*)&hid[q*4];
    acc += w4[0]*h4[0] + w4[1]*h4[1] + w4[2]*h4[2] + w4[3]*h4[3];
  }
  bias_all[b*HID + d] = acc + w_en_b[d] + w_de_b[d];
}

// ---------------- kernel 2 (fast): m97-structure GEMM + T2 XOR swizzle ----------------
// LDS physical slot s' of row r holds logical 16B-slot s = s'^(r&7)  (slot = 16B unit, 8/row).
// Staging: linear LDS dest (global_load_lds requirement), inverse-swizzled GLOBAL source.
// Read:    ds_read col XOR'd with (fr&7)<<3 shorts — same involution. (rule #21: both sides)
__global__ void __launch_bounds__(256) k_gemm_score_fast(
    const short* __restrict__ Abf,      // en_output bf16 (M x K)
    const short* __restrict__ Bw,       // w_en bf16 (N x K)
    const float* __restrict__ bias_all, // (BATCH x N)
    const float* __restrict__ v_w,      // (N)
    float* __restrict__ scores)         // (M), pre-zeroed, atomic accumulate
{
  __shared__ short As[BM][BK];   // 16 KB
  __shared__ short Bs[BN][BK];   // 16 KB

  // Same-XCD sibling swizzle: the 8 n-blocks of one m-panel land on one XCD -> A panel fetched once
  int raw  = blockIdx.x;
  int xcd  = raw & 7;
  int idx  = raw >> 3;
  int mblk = xcd * (M_TOT/BM/8) + (idx >> 3);
  int nblk = idx & 7;
  int m0 = mblk * BM, n0 = nblk * BN;

  int tid  = threadIdx.x;
  int lane = tid & 63;
  int wid  = tid >> 6;
  int wr = wid >> 1, wc = wid & 1;
  int fr  = lane & 15;
  int fko = (lane >> 4) * 8;
  int rsw = (fr & 7) << 3;      // read-side XOR (shorts): (row&7)<<3 == byte<<4

  f32x4 acc[4][4] = {};

  for (int kt = 0; kt < NT; ++kt) {
    __syncthreads();   // readers of previous tile done
    #pragma unroll
    for (int j = 0; j < 4; ++j) {
      int c = j*256 + tid;             // 16B chunk: row r=c>>3, physical slot s'=c&7
      int r = c >> 3;
      int s = (c & 7) ^ (r & 7);       // logical slot fetched into physical slot s'
      const short* srcA = Abf + (size_t)(m0 + r) * HID + kt*BK + s*8;
      __builtin_amdgcn_global_load_lds(
          (const __attribute__((address_space(1))) void*)srcA,
          (__attribute__((address_space(3))) void*)((char*)&As[0][0] + c*16),
          16, 0, 0);
    }
    #pragma unroll
    for (int j = 0; j < 4; ++j) {
      int c = j*256 + tid;
      int r = c >> 3;
      int s = (c & 7) ^ (r & 7);
      const short* srcB = Bw + (size_t)(n0 + r) * HID + kt*BK + s*8;
      __builtin_amdgcn_global_load_lds(
          (const __attribute__((address_space(1))) void*)srcB,
          (__attribute__((address_space(3))) void*)((char*)&Bs[0][0] + c*16),
          16, 0, 0);
    }
    __syncthreads();   // vmcnt drained by compiler before barrier

    #pragma unroll
    for (int kk = 0; kk < 2; ++kk) {
      bf16x8 aF[4], bF[4];
      #pragma unroll
      for (int mi = 0; mi < 4; ++mi)
        aF[mi] = *(const bf16x8*)&As[wr*64 + mi*16 + fr][(kk*32 + fko) ^ rsw];
      #pragma unroll
      for (int ni = 0; ni < 4; ++ni)
        bF[ni] = *(const bf16x8*)&Bs[wc*64 + ni*16 + fr][(kk*32 + fko) ^ rsw];
      #pragma unroll
      for (int mi = 0; mi < 4; ++mi)
        #pragma unroll
        for (int ni = 0; ni < 4; ++ni)
          acc[mi][ni] = __builtin_amdgcn_mfma_f32_16x16x32_bf16(aF[mi], bF[ni], acc[mi][ni], 0, 0, 0);
    }
  }

  // Epilogue: energy = tanh(acc + bias), partial score = sum_n energy*v
  int b = m0 >> 11;
  float vv[4], bb[4];
  #pragma unroll
  for (int ni = 0; ni < 4; ++ni) {
    int col = n0 + wc*64 + ni*16 + fr;
    vv[ni] = v_w[col];
    bb[ni] = bias_all[b*HID + col];
  }
  #pragma unroll
  for (int mi = 0; mi < 4; ++mi) {
    #pragma unroll
    for (int j = 0; j < 4; ++j) {
      float p = 0.f;
      #pragma unroll
      for (int ni = 0; ni < 4; ++ni)
        p += tanhf(acc[mi][ni][j] + bb[ni]) * vv[ni];
      p += __shfl_xor(p, 1);
      p += __shfl_xor(p, 2);
      p += __shfl_xor(p, 4);
      p += __shfl_xor(p, 8);
      if (fr == 0) {
        int row = wr*64 + mi*16 + ((lane >> 4) << 2) + j;
        atomicAdd(&scores[m0 + row], p);
      }
    }
  }
}

// ---------------- kernel 2 (fallback): in-kernel A conversion (only if ws too small) ----------------
__global__ void __launch_bounds__(256) k_gemm_score_conv(
    const float* __restrict__ A, const short* __restrict__ Bw,
    const float* __restrict__ bias_all, const float* __restrict__ v_w,
    float* __restrict__ scores)
{
  __shared__ short As[BM][BK];
  __shared__ short Bs[BN][BK];
  int raw  = blockIdx.x;
  int xcd  = raw & 7;
  int idx  = raw >> 3;
  int mblk = xcd * (M_TOT/BM/8) + (idx >> 3);
  int nblk = idx & 7;
  int m0 = mblk * BM, n0 = nblk * BN;
  int tid  = threadIdx.x;
  int lane = tid & 63;
  int wid  = tid >> 6;
  int wr = wid >> 1, wc = wid & 1;
  int fr  = lane & 15;
  int fko = (lane >> 4) * 8;
  f32x4 acc[4][4] = {};
  int ar = tid >> 1;
  int ac = (tid & 1) * 32;
  const float* aBase = A + (size_t)(m0 + ar) * HID + ac;
  f32x4 aReg[8];
  #pragma unroll
  for (int i = 0; i < 8; ++i) aReg[i] = *(const f32x4*)(aBase + i*4);
  for (int kt = 0; kt < NT; ++kt) {
    __syncthreads();
    #pragma unroll
    for (int g = 0; g < 4; ++g) {
      bf16x8 w;
      w[0]=f2bf(aReg[2*g][0]);   w[1]=f2bf(aReg[2*g][1]);
      w[2]=f2bf(aReg[2*g][2]);   w[3]=f2bf(aReg[2*g][3]);
      w[4]=f2bf(aReg[2*g+1][0]); w[5]=f2bf(aReg[2*g+1][1]);
      w[6]=f2bf(aReg[2*g+1][2]); w[7]=f2bf(aReg[2*g+1][3]);
      *(bf16x8*)&As[ar][ac + g*8] = w;
    }
    #pragma unroll
    for (int j = 0; j < 4; ++j) {
      int c = j*256 + tid;
      const short* src = Bw + (size_t)(n0 + (c >> 3)) * HID + kt*BK + (c & 7)*8;
      __builtin_amdgcn_global_load_lds(
          (const __attribute__((address_space(1))) void*)src,
          (__attribute__((address_space(3))) void*)((char*)&Bs[0][0] + c*16),
          16, 0, 0);
    }
    __syncthreads();
    if (kt + 1 < NT) {
      const float* nxt = aBase + (kt+1)*BK;
      #pragma unroll
      for (int i = 0; i < 8; ++i) aReg[i] = *(const f32x4*)(nxt + i*4);
    }
    #pragma unroll
    for (int kk = 0; kk < 2; ++kk) {
      bf16x8 aF[4], bF[4];
      #pragma unroll
      for (int mi = 0; mi < 4; ++mi)
        aF[mi] = *(const bf16x8*)&As[wr*64 + mi*16 + fr][kk*32 + fko];
      #pragma unroll
      for (int ni = 0; ni < 4; ++ni)
        bF[ni] = *(const bf16x8*)&Bs[wc*64 + ni*16 + fr][kk*32 + fko];
      #pragma unroll
      for (int mi = 0; mi < 4; ++mi)
        #pragma unroll
        for (int ni = 0; ni < 4; ++ni)
          acc[mi][ni] = __builtin_amdgcn_mfma_f32_16x16x32_bf16(aF[mi], bF[ni], acc[mi][ni], 0, 0, 0);
    }
  }
  int b = m0 >> 11;
  float vv[4], bb[4];
  #pragma unroll
  for (int ni = 0; ni < 4; ++ni) {
    int col = n0 + wc*64 + ni*16 + fr;
    vv[ni] = v_w[col];
    bb[ni] = bias_all[b*HID + col];
  }
  #pragma unroll
  for (int mi = 0; mi < 4; ++mi) {
    #pragma unroll
    for (int j = 0; j < 4; ++j) {
      float p = 0.f;
      #pragma unroll
      for (int ni = 0; ni < 4; ++ni)
        p += tanhf(acc[mi][ni][j] + bb[ni]) * vv[ni];
      p += __shfl_xor(p, 1);
      p += __shfl_xor(p, 2);
      p += __shfl_xor(p, 4);
      p += __shfl_xor(p, 8);
      if (fr == 0) {
        int row = wr*64 + mi*16 + ((lane >> 4) << 2) + j;
        atomicAdd(&scores[m0 + row], p);
      }
    }
  }
}

// ---------------- kernel 3: in-place softmax over S per batch ----------------
__global__ void k_softmax(float* __restrict__ attn) {
  int b = blockIdx.x;
  float* row = attn + (size_t)b * SRC_LEN;
  int tid = threadIdx.x, lane = tid & 63, wid = tid >> 6;
  __shared__ float red[4];
  float v[8];
  #pragma unroll
  for (int i = 0; i < 8; ++i) v[i] = row[tid + i*256];
  float mx = v[0];
  #pragma unroll
  for (int i = 1; i < 8; ++i) mx = fmaxf(mx, v[i]);
  #pragma unroll
  for (int o = 32; o; o >>= 1) mx = fmaxf(mx, __shfl_xor(mx, o));
  if (lane == 0) red[wid] = mx;
  __syncthreads();
  mx = fmaxf(fmaxf(red[0], red[1]), fmaxf(red[2], red[3]));
  float s = 0.f;
  #pragma unroll
  for (int i = 0; i < 8; ++i) { v[i] = __expf(v[i] - mx); s += v[i]; }
  #pragma unroll
  for (int o = 32; o; o >>= 1) s += __shfl_xor(s, o);
  __syncthreads();
  if (lane == 0) red[wid] = s;
  __syncthreads();
  s = red[0] + red[1] + red[2] + red[3];
  float inv = 1.f / s;
  #pragma unroll
  for (int i = 0; i < 8; ++i) row[tid + i*256] = v[i] * inv;
}

// ---------------- kernel 4: weighted[b,e] = sum_s attn[b,s] * en[b,s,e] ----------------
__global__ void k_weighted(const float* __restrict__ en, const float* __restrict__ attn,
                           float* __restrict__ outw) {
  int b  = blockIdx.x >> 4;
  int sc = blockIdx.x & 15;
  __shared__ float aw[128];
  int tid = threadIdx.x;
  if (tid < 128) aw[tid] = attn[b*SRC_LEN + sc*128 + tid];
  __syncthreads();
  const float* base = en + ((size_t)b*SRC_LEN + sc*128) * HID + tid*4;
  f32x4 acc = {0.f, 0.f, 0.f, 0.f};
  #pragma unroll 8
  for (int s = 0; s < 128; ++s) {
    f32x4 x = *(const f32x4*)(base + (size_t)s*HID);
    float w = aw[s];
    acc[0] += w*x[0]; acc[1] += w*x[1]; acc[2] += w*x[2]; acc[3] += w*x[3];
  }
  float* o = outw + b*HID + tid*4;
  atomicAdd(o+0, acc[0]); atomicAdd(o+1, acc[1]);
  atomicAdd(o+2, acc[2]); atomicAdd(o+3, acc[3]);
}

extern "C" void kernel_launch(void* const* d_in, const int* in_sizes, int n_in,
                              void* d_out, int out_size, void* d_ws, size_t ws_size,
                              hipStream_t stream) {
  const float* hidden = (const float*)d_in[0];
  const float* en     = (const float*)d_in[1];
  const float* w_en_w = (const float*)d_in[2];
  const float* w_en_b = (const float*)d_in[3];
  const float* w_de_w = (const float*)d_in[4];
  const float* w_de_b = (const float*)d_in[5];
  const float* v_w    = (const float*)d_in[6];

  float* outw = (float*)d_out;              // (B, 1, E)
  float* attn = outw + BATCH*HID;           // (B, S) scores -> attention in place

  const size_t en_elems = (size_t)M_TOT * HID;
  const size_t need_fast = en_elems*sizeof(short) + (size_t)HID*HID*sizeof(short)
                         + (size_t)BATCH*HID*sizeof(float);

  hipMemsetAsync(d_out, 0, (size_t)out_size * sizeof(float), stream);

  if (ws_size >= need_fast) {
    short* en_bf    = (short*)d_ws;                       // 256 MB
    short* w_bf     = en_bf + en_elems;                   // 2 MB
    float* bias_all = (float*)(w_bf + (size_t)HID*HID);   // 256 KB

    k_convert_en<<<dim3(2048), dim3(256), 0, stream>>>(en, en_bf);
    k_convert_w<<<dim3(HID*HID/(256*8)), dim3(256), 0, stream>>>(w_en_w, w_bf);
    k_bias<<<dim3(BATCH*4), dim3(256), 0, stream>>>(hidden, w_de_w, w_en_b, w_de_b, bias_all);
    k_gemm_score_fast<<<dim3((M_TOT/BM)*(HID/BN)), dim3(256), 0, stream>>>(en_bf, w_bf, bias_all, v_w, attn);
  } else {
    short* w_bf     = (short*)d_ws;
    float* bias_all = (float*)((char*)d_ws + (size_t)HID*HID*sizeof(short));
    k_convert_w<<<dim3(HID*HID/(256*8)), dim3(256), 0, stream>>>(w_en_w, w_bf);
    k_bias<<<dim3(BATCH*4), dim3(256), 0, stream>>>(hidden, w_de_w, w_en_b, w_de_b, bias_all);
    k_gemm_score_conv<<<dim3((M_TOT/BM)*(HID/BN)), dim3(256), 0, stream>>>(en, w_bf, bias_all, v_w, attn);
  }

  k_softmax<<<dim3(BATCH), dim3(256), 0, stream>>>(attn);
  k_weighted<<<dim3(BATCH*16), dim3(256), 0, stream>>>(en, attn, outw);
}

// Round 4
// 691.072 us; speedup vs baseline: 1.5511x; 1.1367x over previous
//
#include <hip/hip_runtime.h>
#include <stdint.h>

typedef __attribute__((ext_vector_type(4))) float  f32x4;
typedef __attribute__((ext_vector_type(8))) short  bf16x8;

#define BATCH   64
#define SRC_LEN 2048
#define HID     1024
#define M_TOT   (BATCH*SRC_LEN)   // 131072

// 256^2 deep-pipelined GEMM geometry
#define BM 256
#define BN 256
#define BK 64
#define NT (HID/BK)               // 16 K-tiles, 8 iterations x 2

__device__ __forceinline__ short f2bf(float f) {
  unsigned u = __builtin_bit_cast(unsigned, f);
  u += 0x7fffu + ((u >> 16) & 1u);
  return (short)(u >> 16);
}

// ---------------- kernel 0a: w_en_w fp32 -> bf16 (2 MB) ----------------
__global__ void k_convert_w(const float* __restrict__ w, short* __restrict__ wb) {
  int i = (blockIdx.x * 256 + threadIdx.x) * 8;
  f32x4 a = *(const f32x4*)(w + i);
  f32x4 b = *(const f32x4*)(w + i + 4);
  bf16x8 o;
  o[0]=f2bf(a[0]); o[1]=f2bf(a[1]); o[2]=f2bf(a[2]); o[3]=f2bf(a[3]);
  o[4]=f2bf(b[0]); o[5]=f2bf(b[1]); o[6]=f2bf(b[2]); o[7]=f2bf(b[3]);
  *(bf16x8*)(wb + i) = o;
}

// ---------------- kernel 0b: en_output fp32 -> bf16 (256 MB), grid-stride ----------------
__global__ void k_convert_en(const float* __restrict__ in, short* __restrict__ out) {
  size_t stride = (size_t)gridDim.x * 256 * 8;
  size_t base = ((size_t)blockIdx.x * 256 + threadIdx.x) * 8;
  size_t total = (size_t)M_TOT * HID;
  for (; base < total; base += stride) {
    f32x4 a = *(const f32x4*)(in + base);
    f32x4 b = *(const f32x4*)(in + base + 4);
    bf16x8 o;
    o[0]=f2bf(a[0]); o[1]=f2bf(a[1]); o[2]=f2bf(a[2]); o[3]=f2bf(a[3]);
    o[4]=f2bf(b[0]); o[5]=f2bf(b[1]); o[6]=f2bf(b[2]); o[7]=f2bf(b[3]);
    *(bf16x8*)(out + base) = o;
  }
}

// ---------------- kernel 1: bias_all[b][d] = w_en_b + w_de_b + hidden[b]·w_de_w[d] ----------------
__global__ void k_bias(const float* __restrict__ hidden, const float* __restrict__ w_de_w,
                       const float* __restrict__ w_en_b, const float* __restrict__ w_de_b,
                       float* __restrict__ bias_all) {
  __shared__ float hid[HID];
  int b  = blockIdx.x >> 2;
  int dc = blockIdx.x & 3;
  for (int i = threadIdx.x; i < HID; i += 256) hid[i] = hidden[b*HID + i];
  __syncthreads();
  int d = dc*256 + threadIdx.x;
  const f32x4* wrow = (const f32x4*)(w_de_w + (size_t)d*HID);
  float acc = 0.f;
  #pragma unroll 8
  for (int q = 0; q < HID/4; ++q) {
    f32x4 w4 = wrow[q];
    f32x4 h4 = *(const f32x4*)&hid[q*4];
    acc += w4[0]*h4[0] + w4[1]*h4[1] + w4[2]*h4[2] + w4[3]*h4[3];
  }
  bias_all[b*HID + d] = acc + w_en_b[d] + w_de_b[d];
}

// ---------------- kernel 2 (fast): 256^2, 8-wave, double-buffered, counted-vmcnt GEMM ----------------
// T1 XCD swizzle, T2 XOR swizzle (both-sides, proven 0-conflict in r3), T3/T4 counted vmcnt(8)
// (next tile's loads stay in flight across barriers; vmcnt(0) only on the last iteration),
// T5 setprio around each 16-MFMA quadrant.
__global__ void __launch_bounds__(512, 2) k_gemm_score_fast(
    const short* __restrict__ Abf,      // en_output bf16 (M x K)
    const short* __restrict__ Bw,       // w_en bf16 (N x K)
    const float* __restrict__ bias_all, // (BATCH x N)
    const float* __restrict__ v_w,      // (N)
    float* __restrict__ scores)         // (M), pre-zeroed, atomic accumulate
{
  __shared__ short As[2][BM][BK];   // 64 KB
  __shared__ short Bs[2][BN][BK];   // 64 KB

  // T1: 2048 blocks; 256 consecutive ids per XCD -> one XCD owns 64 m-panels x 4 n-blocks
  int raw  = blockIdx.x;
  int xcd  = raw & 7;
  int idx  = raw >> 3;                  // 0..255
  int mblk = xcd * 64 + (idx >> 2);     // 512 m-panels total, 64 per XCD
  int nblk = idx & 3;                   // 4 n-blocks share this m-panel's A (L2 reuse)
  int m0 = mblk * BM, n0 = nblk * BN;

  int tid  = threadIdx.x;
  int lane = tid & 63;
  int wid  = tid >> 6;           // 8 waves: 2 (m) x 4 (n)
  int wm = wid >> 2, wn = wid & 3;
  int fr  = lane & 15;
  int fko = (lane >> 4) * 8;
  int rsw = (fr & 7) << 3;       // read-side XOR in shorts

  f32x4 acc[8][4] = {};          // wave tile 128x64: 8 m-frags x 4 n-frags

  // stage one K-tile (A: 256x64, B: 256x64) -> buf; 8 global_load_lds per thread
  auto stage = [&](int buf, int kt) {
    #pragma unroll
    for (int q = 0; q < 4; ++q) {
      int c = q*512 + tid;             // 16B chunk id in [0,2048)
      int r = c >> 3;
      int s = (c & 7) ^ (r & 7);       // inverse swizzle on global source
      const short* srcA = Abf + (size_t)(m0 + r) * HID + kt*BK + s*8;
      __builtin_amdgcn_global_load_lds(
          (const __attribute__((address_space(1))) void*)srcA,
          (__attribute__((address_space(3))) void*)((char*)&As[buf][0][0] + c*16),
          16, 0, 0);
    }
    #pragma unroll
    for (int q = 0; q < 4; ++q) {
      int c = q*512 + tid;
      int r = c >> 3;
      int s = (c & 7) ^ (r & 7);
      const short* srcB = Bw + (size_t)(n0 + r) * HID + kt*BK + s*8;
      __builtin_amdgcn_global_load_lds(
          (const __attribute__((address_space(1))) void*)srcB,
          (__attribute__((address_space(3))) void*)((char*)&Bs[buf][0][0] + c*16),
          16, 0, 0);
    }
  };

  // compute one K-tile from buf: 4 quadrant phases q00 -> q01 -> q11 -> q10
  auto compute = [&](int buf) {
    bf16x8 aF[8], bF[4];
    // load A-frags for mq (4 mi x 2 kk) and B-frags for nq (2 ni x 2 kk)
    #define LDA(mq) { _Pragma("unroll") for (int mi = 0; mi < 4; ++mi) \
        _Pragma("unroll") for (int kk = 0; kk < 2; ++kk) \
          aF[mi*2+kk] = *(const bf16x8*)&As[buf][wm*128 + (mq)*64 + mi*16 + fr][(kk*32 + fko) ^ rsw]; }
    #define LDB(nq) { _Pragma("unroll") for (int ni = 0; ni < 2; ++ni) \
        _Pragma("unroll") for (int kk = 0; kk < 2; ++kk) \
          bF[ni*2+kk] = *(const bf16x8*)&Bs[buf][wn*64 + (nq)*32 + ni*16 + fr][(kk*32 + fko) ^ rsw]; }
    #define MM(mq,nq) { __builtin_amdgcn_s_setprio(1); \
        _Pragma("unroll") for (int mi = 0; mi < 4; ++mi) \
        _Pragma("unroll") for (int ni = 0; ni < 2; ++ni) \
        _Pragma("unroll") for (int kk = 0; kk < 2; ++kk) \
          acc[(mq)*4+mi][(nq)*2+ni] = __builtin_amdgcn_mfma_f32_16x16x32_bf16( \
              aF[mi*2+kk], bF[ni*2+kk], acc[(mq)*4+mi][(nq)*2+ni], 0, 0, 0); \
        __builtin_amdgcn_s_setprio(0); }
    LDA(0); LDB(0); MM(0,0);
    LDB(1);         MM(0,1);
    LDA(1);         MM(1,1);
    LDB(0);         MM(1,0);
    #undef LDA
    #undef LDB
    #undef MM
  };

  stage(0, 0);                               // prologue: 8 loads in flight
  for (int it = 0; it < 8; ++it) {
    stage(1, 2*it + 1);                      // outstanding: buf0's 8 (old) + buf1's 8 (new)
    asm volatile("s_waitcnt vmcnt(8)" ::: "memory");   // buf0's loads done, buf1's flying
    __builtin_amdgcn_s_barrier();            // every wave waited its own -> buf0 globally ready
    compute(0);                              // tile 2it
    asm volatile("s_waitcnt lgkmcnt(0)" ::: "memory");
    __builtin_amdgcn_s_barrier();            // all waves done reading buf0
    if (it < 7) {
      stage(0, 2*it + 2);                    // restage buf0; outstanding: buf1's 8 + buf0's 8
      asm volatile("s_waitcnt vmcnt(8)" ::: "memory"); // buf1 done, buf0-next flying
    } else {
      asm volatile("s_waitcnt vmcnt(0)" ::: "memory"); // nothing else in flight
    }
    __builtin_amdgcn_s_barrier();
    compute(1);                              // tile 2it+1
    if (it < 7) {
      asm volatile("s_waitcnt lgkmcnt(0)" ::: "memory");
      __builtin_amdgcn_s_barrier();          // all waves done reading buf1 before next restage
    }
  }

  // Epilogue: energy = tanh(acc + bias), partial score = sum over wave's 64 cols
  int b = m0 >> 11;                          // 2048 rows per batch; 256 | 2048
  float vv[4], bb[4];
  #pragma unroll
  for (int nf = 0; nf < 4; ++nf) {
    int col = n0 + wn*64 + nf*16 + fr;
    vv[nf] = v_w[col];
    bb[nf] = bias_all[b*HID + col];
  }
  #pragma unroll
  for (int mf = 0; mf < 8; ++mf) {
    #pragma unroll
    for (int j = 0; j < 4; ++j) {
      float p = 0.f;
      #pragma unroll
      for (int nf = 0; nf < 4; ++nf)
        p += tanhf(acc[mf][nf][j] + bb[nf]) * vv[nf];
      p += __shfl_xor(p, 1);
      p += __shfl_xor(p, 2);
      p += __shfl_xor(p, 4);
      p += __shfl_xor(p, 8);
      if (fr == 0) {
        int row = wm*128 + mf*16 + ((lane >> 4) << 2) + j;
        atomicAdd(&scores[m0 + row], p);
      }
    }
  }
}

// ---------------- kernel 2 (fallback): 128^2 with in-kernel A conversion (ws too small) ----------------
__global__ void __launch_bounds__(256) k_gemm_score_conv(
    const float* __restrict__ A, const short* __restrict__ Bw,
    const float* __restrict__ bias_all, const float* __restrict__ v_w,
    float* __restrict__ scores)
{
  __shared__ short Asl[128][64];
  __shared__ short Bsl[128][64];
  int raw  = blockIdx.x;
  int xcd  = raw & 7;
  int idx  = raw >> 3;
  int mblk = xcd * (M_TOT/128/8) + (idx >> 3);
  int nblk = idx & 7;
  int m0 = mblk * 128, n0 = nblk * 128;
  int tid  = threadIdx.x;
  int lane = tid & 63;
  int wid  = tid >> 6;
  int wr = wid >> 1, wc = wid & 1;
  int fr  = lane & 15;
  int fko = (lane >> 4) * 8;
  f32x4 acc[4][4] = {};
  int ar = tid >> 1;
  int ac = (tid & 1) * 32;
  const float* aBase = A + (size_t)(m0 + ar) * HID + ac;
  f32x4 aReg[8];
  #pragma unroll
  for (int i = 0; i < 8; ++i) aReg[i] = *(const f32x4*)(aBase + i*4);
  for (int kt = 0; kt < 16; ++kt) {
    __syncthreads();
    #pragma unroll
    for (int g = 0; g < 4; ++g) {
      bf16x8 w;
      w[0]=f2bf(aReg[2*g][0]);   w[1]=f2bf(aReg[2*g][1]);
      w[2]=f2bf(aReg[2*g][2]);   w[3]=f2bf(aReg[2*g][3]);
      w[4]=f2bf(aReg[2*g+1][0]); w[5]=f2bf(aReg[2*g+1][1]);
      w[6]=f2bf(aReg[2*g+1][2]); w[7]=f2bf(aReg[2*g+1][3]);
      *(bf16x8*)&Asl[ar][ac + g*8] = w;
    }
    #pragma unroll
    for (int j = 0; j < 4; ++j) {
      int c = j*256 + tid;
      const short* src = Bw + (size_t)(n0 + (c >> 3)) * HID + kt*64 + (c & 7)*8;
      __builtin_amdgcn_global_load_lds(
          (const __attribute__((address_space(1))) void*)src,
          (__attribute__((address_space(3))) void*)((char*)&Bsl[0][0] + c*16),
          16, 0, 0);
    }
    __syncthreads();
    if (kt + 1 < 16) {
      const float* nxt = aBase + (kt+1)*64;
      #pragma unroll
      for (int i = 0; i < 8; ++i) aReg[i] = *(const f32x4*)(nxt + i*4);
    }
    #pragma unroll
    for (int kk = 0; kk < 2; ++kk) {
      bf16x8 aF[4], bF[4];
      #pragma unroll
      for (int mi = 0; mi < 4; ++mi)
        aF[mi] = *(const bf16x8*)&Asl[wr*64 + mi*16 + fr][kk*32 + fko];
      #pragma unroll
      for (int ni = 0; ni < 4; ++ni)
        bF[ni] = *(const bf16x8*)&Bsl[wc*64 + ni*16 + fr][kk*32 + fko];
      #pragma unroll
      for (int mi = 0; mi < 4; ++mi)
        #pragma unroll
        for (int ni = 0; ni < 4; ++ni)
          acc[mi][ni] = __builtin_amdgcn_mfma_f32_16x16x32_bf16(aF[mi], bF[ni], acc[mi][ni], 0, 0, 0);
    }
  }
  int b = m0 >> 11;
  float vv[4], bb[4];
  #pragma unroll
  for (int ni = 0; ni < 4; ++ni) {
    int col = n0 + wc*64 + ni*16 + fr;
    vv[ni] = v_w[col];
    bb[ni] = bias_all[b*HID + col];
  }
  #pragma unroll
  for (int mi = 0; mi < 4; ++mi) {
    #pragma unroll
    for (int j = 0; j < 4; ++j) {
      float p = 0.f;
      #pragma unroll
      for (int ni = 0; ni < 4; ++ni)
        p += tanhf(acc[mi][ni][j] + bb[ni]) * vv[ni];
      p += __shfl_xor(p, 1);
      p += __shfl_xor(p, 2);
      p += __shfl_xor(p, 4);
      p += __shfl_xor(p, 8);
      if (fr == 0) {
        int row = wr*64 + mi*16 + ((lane >> 4) << 2) + j;
        atomicAdd(&scores[m0 + row], p);
      }
    }
  }
}

// ---------------- kernel 3: in-place softmax over S per batch ----------------
__global__ void k_softmax(float* __restrict__ attn) {
  int b = blockIdx.x;
  float* row = attn + (size_t)b * SRC_LEN;
  int tid = threadIdx.x, lane = tid & 63, wid = tid >> 6;
  __shared__ float red[4];
  float v[8];
  #pragma unroll
  for (int i = 0; i < 8; ++i) v[i] = row[tid + i*256];
  float mx = v[0];
  #pragma unroll
  for (int i = 1; i < 8; ++i) mx = fmaxf(mx, v[i]);
  #pragma unroll
  for (int o = 32; o; o >>= 1) mx = fmaxf(mx, __shfl_xor(mx, o));
  if (lane == 0) red[wid] = mx;
  __syncthreads();
  mx = fmaxf(fmaxf(red[0], red[1]), fmaxf(red[2], red[3]));
  float s = 0.f;
  #pragma unroll
  for (int i = 0; i < 8; ++i) { v[i] = __expf(v[i] - mx); s += v[i]; }
  #pragma unroll
  for (int o = 32; o; o >>= 1) s += __shfl_xor(s, o);
  __syncthreads();
  if (lane == 0) red[wid] = s;
  __syncthreads();
  s = red[0] + red[1] + red[2] + red[3];
  float inv = 1.f / s;
  #pragma unroll
  for (int i = 0; i < 8; ++i) row[tid + i*256] = v[i] * inv;
}

// ---------------- kernel 4: weighted[b,e] = sum_s attn[b,s] * en[b,s,e] ----------------
__global__ void k_weighted(const float* __restrict__ en, const float* __restrict__ attn,
                           float* __restrict__ outw) {
  int b  = blockIdx.x >> 4;
  int sc = blockIdx.x & 15;
  __shared__ float aw[128];
  int tid = threadIdx.x;
  if (tid < 128) aw[tid] = attn[b*SRC_LEN + sc*128 + tid];
  __syncthreads();
  const float* base = en + ((size_t)b*SRC_LEN + sc*128) * HID + tid*4;
  f32x4 acc = {0.f, 0.f, 0.f, 0.f};
  #pragma unroll 8
  for (int s = 0; s < 128; ++s) {
    f32x4 x = *(const f32x4*)(base + (size_t)s*HID);
    float w = aw[s];
    acc[0] += w*x[0]; acc[1] += w*x[1]; acc[2] += w*x[2]; acc[3] += w*x[3];
  }
  float* o = outw + b*HID + tid*4;
  atomicAdd(o+0, acc[0]); atomicAdd(o+1, acc[1]);
  atomicAdd(o+2, acc[2]); atomicAdd(o+3, acc[3]);
}

extern "C" void kernel_launch(void* const* d_in, const int* in_sizes, int n_in,
                              void* d_out, int out_size, void* d_ws, size_t ws_size,
                              hipStream_t stream) {
  const float* hidden = (const float*)d_in[0];
  const float* en     = (const float*)d_in[1];
  const float* w_en_w = (const float*)d_in[2];
  const float* w_en_b = (const float*)d_in[3];
  const float* w_de_w = (const float*)d_in[4];
  const float* w_de_b = (const float*)d_in[5];
  const float* v_w    = (const float*)d_in[6];

  float* outw = (float*)d_out;              // (B, 1, E)
  float* attn = outw + BATCH*HID;           // (B, S) scores -> attention in place

  const size_t en_elems = (size_t)M_TOT * HID;
  const size_t need_fast = en_elems*sizeof(short) + (size_t)HID*HID*sizeof(short)
                         + (size_t)BATCH*HID*sizeof(float);

  hipMemsetAsync(d_out, 0, (size_t)out_size * sizeof(float), stream);

  if (ws_size >= need_fast) {
    short* en_bf    = (short*)d_ws;                       // 256 MB
    short* w_bf     = en_bf + en_elems;                   // 2 MB
    float* bias_all = (float*)(w_bf + (size_t)HID*HID);   // 256 KB

    k_convert_en<<<dim3(2048), dim3(256), 0, stream>>>(en, en_bf);
    k_convert_w<<<dim3(HID*HID/(256*8)), dim3(256), 0, stream>>>(w_en_w, w_bf);
    k_bias<<<dim3(BATCH*4), dim3(256), 0, stream>>>(hidden, w_de_w, w_en_b, w_de_b, bias_all);
    k_gemm_score_fast<<<dim3((M_TOT/BM)*(HID/BN)), dim3(512), 0, stream>>>(en_bf, w_bf, bias_all, v_w, attn);
  } else {
    short* w_bf     = (short*)d_ws;
    float* bias_all = (float*)((char*)d_ws + (size_t)HID*HID*sizeof(short));
    k_convert_w<<<dim3(HID*HID/(256*8)), dim3(256), 0, stream>>>(w_en_w, w_bf);
    k_bias<<<dim3(BATCH*4), dim3(256), 0, stream>>>(hidden, w_de_w, w_en_b, w_de_b, bias_all);
    k_gemm_score_conv<<<dim3((M_TOT/128)*(HID/128)), dim3(256), 0, stream>>>(en, w_bf, bias_all, v_w, attn);
  }

  k_softmax<<<dim3(BATCH), dim3(256), 0, stream>>>(attn);
  k_weighted<<<dim3(BATCH*16), dim3(256), 0, stream>>>(en, attn, outw);
}